// Round 1
// baseline (656.558 us; speedup 1.0000x reference)
//
#include <hip/hip_runtime.h>
#include <math.h>
#include <stdint.h>

#define BB 8
#define NN 16384
#define CC 80
#define TT 100

// ---------- helpers ----------
__device__ __forceinline__ void argmax_reduce64(float& v, int& i) {
#pragma unroll
  for (int d = 1; d < 64; d <<= 1) {
    float ov = __shfl_xor(v, d);
    int   oi = __shfl_xor(i, d);
    if (ov > v || (ov == v && oi < i)) { v = ov; i = oi; }
  }
}

// ---------- K1: transpose + threshold: scores (B,N,C) -> ts (B,C,N) ----------
__global__ __launch_bounds__(256) void transpose_scores(const float* __restrict__ scores,
                                                        float* __restrict__ ts) {
  __shared__ float tile[64][81];   // 64 n x 80 c, padded
  int blk = blockIdx.x;            // b*256 + ntile
  int b  = blk >> 8;
  int n0 = (blk & 255) << 6;
  const float* src = scores + ((size_t)b * NN + n0) * CC;   // 5120 contiguous floats
#pragma unroll
  for (int it = 0; it < 20; ++it) {
    int idx = it * 256 + threadIdx.x;        // < 5120, coalesced read
    float v = src[idx];
    tile[idx / 80][idx % 80] = v;
  }
  __syncthreads();
#pragma unroll
  for (int it = 0; it < 20; ++it) {
    int idx = it * 256 + threadIdx.x;
    int cc = idx >> 6, nn = idx & 63;        // consecutive tid -> consecutive nn (coalesced write)
    float v = tile[nn][cc];
    ts[((size_t)b * CC + cc) * NN + n0 + nn] = (v > 0.3f) ? v : -INFINITY;
  }
}

// ---------- K2: per-(b,c) lazy-greedy NMS, one wave per block ----------
__global__ __launch_bounds__(64) void nms_kernel(const float* __restrict__ boxes,
                                                 const float* __restrict__ scores,
                                                 const float* __restrict__ ts,
                                                 int use_ts,
                                                 float* __restrict__ det_score,
                                                 float* __restrict__ det_box) {
  __shared__ float bmax[256];                  // max of each 64-entry block
  __shared__ unsigned long long pmask[256];    // popped bits per block
  __shared__ float sy1[TT], sx1[TT], sy2[TT], sx2[TT];

  int bc = blockIdx.x;            // b*CC + c
  int b = bc / CC, c = bc % CC;
  int lane = threadIdx.x;
  const float* tsrc = ts + (size_t)bc * NN;

  // init masks
  pmask[lane] = 0ull; pmask[64 + lane] = 0ull; pmask[128 + lane] = 0ull; pmask[192 + lane] = 0ull;

  // build block maxes
  if (use_ts) {
    const float4* ts4 = (const float4*)tsrc;
#pragma unroll 4
    for (int it = 0; it < 64; ++it) {
      float4 q = ts4[it * 64 + lane];          // elements it*256 + lane*4 ..+3
      float m = fmaxf(fmaxf(q.x, q.y), fmaxf(q.z, q.w));
#pragma unroll
      for (int d = 1; d < 16; d <<= 1) m = fmaxf(m, __shfl_xor(m, d));
      if ((lane & 15) == 0) bmax[it * 4 + (lane >> 4)] = m;
    }
  } else {
    for (int j = 0; j < 256; ++j) {
      float v = scores[((size_t)b * NN + j * 64 + lane) * CC + c];
      v = (v > 0.3f) ? v : -INFINITY;
#pragma unroll
      for (int d = 1; d < 64; d <<= 1) v = fmaxf(v, __shfl_xor(v, d));
      if (lane == 0) bmax[j] = v;
    }
  }
  __builtin_amdgcn_wave_barrier();

  float* dsc = det_score + (size_t)bc * TT;
  float4* dbx = (float4*)det_box + (size_t)bc * TT;
  int nsel = 0;

  while (nsel < TT) {
    // argmax over 256 block maxes (tie -> smaller block)
    float bv = bmax[lane]; int bj = lane;
#pragma unroll
    for (int q = 1; q < 4; ++q) {
      int j2 = q * 64 + lane;
      float v2 = bmax[j2];
      if (v2 > bv || (v2 == bv && j2 < bj)) { bv = v2; bj = j2; }
    }
    argmax_reduce64(bv, bj);
    if (bv == -INFINITY) break;     // exhausted

    // rescan block bj (contiguous 64, coalesced)
    int idx = bj * 64 + lane;
    float v;
    if (use_ts) v = tsrc[idx];
    else {
      v = scores[((size_t)b * NN + idx) * CC + c];
      v = (v > 0.3f) ? v : -INFINITY;
    }
    if ((pmask[bj] >> lane) & 1ull) v = -INFINITY;
    float vv = v; int ii = lane;
    argmax_reduce64(vv, ii);        // tie -> smaller lane => smaller global idx
    int top = bj * 64 + ii;

    // mark popped + update block max (recompute from registers)
    if (lane == 0) pmask[bj] |= (1ull << ii);
    float v3 = (lane == ii) ? -INFINITY : v;
#pragma unroll
    for (int d = 1; d < 64; d <<= 1) v3 = fmaxf(v3, __shfl_xor(v3, d));
    if (lane == 0) bmax[bj] = v3;
    __builtin_amdgcn_wave_barrier();

    // fetch candidate box (broadcast load)
    float4 bx = *(const float4*)(boxes + ((size_t)b * NN + top) * 4);
    float by1 = bx.x, bx1 = bx.y, by2 = bx.z, bx2 = bx.w;
    float areac = fmaxf(by2 - by1, 0.0f) * fmaxf(bx2 - bx1, 0.0f);

    // IoU vs selected set (lane l checks s = l, l+64)
    int sup = 0;
    for (int s = lane; s < nsel; s += 64) {
      float a1 = sy1[s], a2 = sx1[s], a3 = sy2[s], a4 = sx2[s];
      float yy1 = fmaxf(by1, a1), xx1 = fmaxf(bx1, a2);
      float yy2 = fminf(by2, a3), xx2 = fminf(bx2, a4);
      float inter = fmaxf(yy2 - yy1, 0.0f) * fmaxf(xx2 - xx1, 0.0f);
      float areas = fmaxf(a3 - a1, 0.0f) * fmaxf(a4 - a2, 0.0f);
      float uni = areac + areas - inter;
      if (inter / fmaxf(uni, 1e-9f) >= 0.5f) sup = 1;
    }
    if (!__any(sup)) {
      if (lane == 0) {
        sy1[nsel] = by1; sx1[nsel] = bx1; sy2[nsel] = by2; sx2[nsel] = bx2;
        dsc[nsel] = vv;
        dbx[nsel] = bx;
      }
      __builtin_amdgcn_wave_barrier();
      nsel++;
    }
  }
  // fill remaining slots: kept=false sentinel
  for (int t = nsel + lane; t < TT; t += 64) dsc[t] = -INFINITY;
}

// ---------- K3: per-batch top-100 of 8000 with lax.top_k tie semantics ----------
__global__ __launch_bounds__(256) void topk_kernel(const float* __restrict__ det_score,
                                                   const float* __restrict__ det_box,
                                                   float* __restrict__ out) {
  __shared__ float ds[CC * TT];          // 8000 floats
  __shared__ float rv[4];
  __shared__ int   ri[4];
  int b = blockIdx.x, tid = threadIdx.x;
  for (int i = tid; i < CC * TT; i += 256) ds[i] = det_score[(size_t)b * CC * TT + i];
  __syncthreads();

  float* ob = out + (size_t)b * TT * 4;           // boxes  [0,3200)
  float* os = out + 3200 + (size_t)b * TT;        // scores [3200,4000)
  float* ol = out + 4000 + (size_t)b * TT;        // labels [4000,4800) as float
  int vcount = 0;

  for (int r = 0; r < TT; ++r) {
    float v = -INFINITY; int i = 0x7fffffff;
#pragma unroll
    for (int k = 0; k < 32; ++k) {
      int j = k * 256 + tid;
      if (j < CC * TT) {
        float x = ds[j];
        if (x > v || (x == v && j < i)) { v = x; i = j; }
      }
    }
    argmax_reduce64(v, i);
    if ((tid & 63) == 0) { rv[tid >> 6] = v; ri[tid >> 6] = i; }
    __syncthreads();
    if (tid == 0) {
      float wv = rv[0]; int wi = ri[0];
#pragma unroll
      for (int w = 1; w < 4; ++w)
        if (rv[w] > wv || (rv[w] == wv && ri[w] < wi)) { wv = rv[w]; wi = ri[w]; }
      int valid = (wv != -INFINITY);
      if (valid) {
        float4 bx = *(const float4*)(det_box + ((size_t)b * CC * TT + wi) * 4);
        ob[r * 4 + 0] = bx.x; ob[r * 4 + 1] = bx.y; ob[r * 4 + 2] = bx.z; ob[r * 4 + 3] = bx.w;
        os[r] = wv;
        ol[r] = (float)(wi / TT);
        vcount++;
      } else {
        ob[r * 4 + 0] = 0.0f; ob[r * 4 + 1] = 0.0f; ob[r * 4 + 2] = 0.0f; ob[r * 4 + 3] = 0.0f;
        os[r] = 0.0f;
        ol[r] = 0.0f;
      }
      ds[wi] = -INFINITY;   // pop
    }
    __syncthreads();
  }
  if (tid == 0) out[4800 + b] = (float)vcount;
}

// ---------- launch ----------
extern "C" void kernel_launch(void* const* d_in, const int* in_sizes, int n_in,
                              void* d_out, int out_size, void* d_ws, size_t ws_size,
                              hipStream_t stream) {
  const float* boxes  = (const float*)d_in[0];   // (8,16384,4)
  const float* scores = (const float*)d_in[1];   // (8,16384,80)
  float* out = (float*)d_out;                    // 4808 floats

  const size_t TS_BYTES  = (size_t)BB * CC * NN * 4;         // 41,943,040
  const size_t DSC_BYTES = (size_t)BB * CC * TT * 4;         // 256,000
  // path A: [ts | det_score | det_box]; path B: [det_score | det_box]
  int use_ts = (ws_size >= TS_BYTES + DSC_BYTES + (size_t)BB * CC * TT * 16) ? 1 : 0;

  char* ws = (char*)d_ws;
  float* ts        = use_ts ? (float*)ws : nullptr;
  float* det_score = (float*)(ws + (use_ts ? TS_BYTES : 0));
  float* det_box   = (float*)(ws + (use_ts ? TS_BYTES : 0) + DSC_BYTES);

  if (use_ts) {
    transpose_scores<<<BB * (NN / 64), 256, 0, stream>>>(scores, ts);
  }
  nms_kernel<<<BB * CC, 64, 0, stream>>>(boxes, scores, ts, use_ts, det_score, det_box);
  topk_kernel<<<BB, 256, 0, stream>>>(det_score, det_box, out);
}

// Round 2
// 327.939 us; speedup vs baseline: 2.0021x; 2.0021x over previous
//
#include <hip/hip_runtime.h>
#include <math.h>
#include <stdint.h>

#define BB 8
#define NN 16384
#define CC 80
#define TT 100
#define CAP 1024

typedef unsigned int u32;
typedef unsigned long long u64;

__device__ __forceinline__ void argmax_f_i(float& v, int& i) {
#pragma unroll
  for (int d = 1; d < 64; d <<= 1) {
    float ov = __shfl_xor(v, d);
    int   oi = __shfl_xor(i, d);
    if (ov > v || (ov == v && oi < i)) { v = ov; i = oi; }
  }
}

// ---------- K1: transpose + threshold: scores (B,N,C) -> ts (B,C,N) ----------
__global__ __launch_bounds__(256) void transpose_scores(const float* __restrict__ scores,
                                                        float* __restrict__ ts) {
  __shared__ float tile[64][81];
  int blk = blockIdx.x;
  int b  = blk >> 8;
  int n0 = (blk & 255) << 6;
  const float* src = scores + ((size_t)b * NN + n0) * CC;
#pragma unroll
  for (int it = 0; it < 20; ++it) {
    int idx = it * 256 + threadIdx.x;
    float v = src[idx];
    tile[idx / 80][idx % 80] = v;
  }
  __syncthreads();
#pragma unroll
  for (int it = 0; it < 20; ++it) {
    int idx = it * 256 + threadIdx.x;
    int cc = idx >> 6, nn = idx & 63;
    float v = tile[nn][cc];
    ts[((size_t)b * CC + cc) * NN + n0 + nn] = (v > 0.3f) ? v : -INFINITY;
  }
}

// ---------- K2: per-(b,c) NMS: band-gather -> bitonic sort -> serial greedy ----------
__global__ __launch_bounds__(64) void nms_kernel(const float* __restrict__ boxes,
                                                 const float* __restrict__ scores,
                                                 const float* __restrict__ ts,
                                                 int use_ts,
                                                 float* __restrict__ det_score,
                                                 float* __restrict__ det_box) {
  __shared__ u64 keys[CAP];       // (fbits(v)<<32) | ~idx  -> sort desc = (v desc, idx asc)
  __shared__ float4 bxs[CAP];     // boxes in sorted order
  __shared__ int cnt_s;

  int bc = blockIdx.x;
  int b = bc / CC, c = bc % CC;
  int lane = threadIdx.x;
  const float* tsrc = ts + (size_t)bc * NN;
  const float* bsrc = boxes + (size_t)b * NN * 4;
  float* dsc = det_score + (size_t)bc * TT;
  float4* dbx = (float4*)det_box + (size_t)bc * TT;

  int nsel = 0;
  float4 sb0 = make_float4(0.f, 0.f, 0.f, 0.f);
  float4 sb1 = make_float4(0.f, 0.f, 0.f, 0.f);
  float sa0 = 0.f, sa1 = 0.f;

  float cur_hi = INFINITY;
  float lo = 0.97f;
  bool done = false;

  while (!done) {
    // ---- gather band [lo, cur_hi)
    int cnt;
    float wmax = -INFINITY;
    int tries = 0;
    for (;;) {
      if (lane == 0) cnt_s = 0;
      __builtin_amdgcn_wave_barrier();
      if (use_ts) {
        const float4* ts4 = (const float4*)tsrc;
        for (int it = 0; it < 64; ++it) {
          float4 q = ts4[it * 64 + lane];
          int base = (it * 64 + lane) * 4;
          float vv0 = q.x, vv1 = q.y, vv2 = q.z, vv3 = q.w;
          wmax = fmaxf(fmaxf(wmax, fmaxf(vv0, vv1)), fmaxf(vv2, vv3));
          if (vv0 >= lo && vv0 < cur_hi) {
            int s = atomicAdd(&cnt_s, 1);
            if (s < CAP) keys[s] = ((u64)__float_as_uint(vv0) << 32) | (u32)(~(u32)(base + 0));
          }
          if (vv1 >= lo && vv1 < cur_hi) {
            int s = atomicAdd(&cnt_s, 1);
            if (s < CAP) keys[s] = ((u64)__float_as_uint(vv1) << 32) | (u32)(~(u32)(base + 1));
          }
          if (vv2 >= lo && vv2 < cur_hi) {
            int s = atomicAdd(&cnt_s, 1);
            if (s < CAP) keys[s] = ((u64)__float_as_uint(vv2) << 32) | (u32)(~(u32)(base + 2));
          }
          if (vv3 >= lo && vv3 < cur_hi) {
            int s = atomicAdd(&cnt_s, 1);
            if (s < CAP) keys[s] = ((u64)__float_as_uint(vv3) << 32) | (u32)(~(u32)(base + 3));
          }
        }
      } else {
        for (int it = 0; it < 256; ++it) {
          int n = it * 64 + lane;
          float v = scores[((size_t)b * NN + n) * CC + c];
          v = (v > 0.3f) ? v : -INFINITY;
          wmax = fmaxf(wmax, v);
          if (v >= lo && v < cur_hi) {
            int s = atomicAdd(&cnt_s, 1);
            if (s < CAP) keys[s] = ((u64)__float_as_uint(v) << 32) | (u32)(~(u32)n);
          }
        }
      }
      __builtin_amdgcn_wave_barrier();
      cnt = cnt_s;
      if (cnt <= CAP || tries >= 8) { if (cnt > CAP) cnt = CAP; break; }
      float m = wmax;
#pragma unroll
      for (int d = 1; d < 64; d <<= 1) m = fmaxf(m, __shfl_xor(m, d));
      float hi_eff = isinf(cur_hi) ? m : cur_hi;
      lo = 0.5f * (lo + hi_eff);
      ++tries;
    }

    if (cnt > 0) {
      // pad to power of two
      int n2 = 64;
      while (n2 < cnt) n2 <<= 1;
      for (int s = cnt + lane; s < n2; s += 64) keys[s] = 0ull;
      {
        // fix striding: cover [cnt, n2) with all lanes
      }
      __builtin_amdgcn_wave_barrier();
      // ---- bitonic sort descending, single wave, no barriers needed (LDS in-order per wave)
      for (int k = 2; k <= n2; k <<= 1) {
        for (int j = k >> 1; j > 0; j >>= 1) {
          for (int i = lane; i < n2; i += 64) {
            int ixj = i ^ j;
            if (ixj > i) {
              u64 a = keys[i], d2 = keys[ixj];
              bool up = ((i & k) == 0);
              if (up ? (a < d2) : (a > d2)) { keys[i] = d2; keys[ixj] = a; }
            }
          }
          __builtin_amdgcn_wave_barrier();
        }
      }
      // ---- prefetch candidate boxes in sorted order
      for (int s = lane; s < cnt; s += 64) {
        u32 g = ~(u32)keys[s];
        bxs[s] = *(const float4*)(bsrc + (size_t)g * 4);
      }
      __builtin_amdgcn_wave_barrier();
      // ---- serial greedy; lane l caches selected slots l and 64+l in registers
      for (int s = 0; s < cnt && nsel < TT; ++s) {
        u64 key = keys[s];
        float4 bx = bxs[s];
        float v = __uint_as_float((u32)(key >> 32));
        float by1 = bx.x, bxx1 = bx.y, by2 = bx.z, bxx2 = bx.w;
        float areac = fmaxf(by2 - by1, 0.f) * fmaxf(bxx2 - bxx1, 0.f);
        int sup = 0;
        if (lane < nsel) {
          float yy1 = fmaxf(sb0.x, by1), xx1 = fmaxf(sb0.y, bxx1);
          float yy2 = fminf(sb0.z, by2), xx2 = fminf(sb0.w, bxx2);
          float inter = fmaxf(yy2 - yy1, 0.f) * fmaxf(xx2 - xx1, 0.f);
          float uni = sa0 + areac - inter;
          if (inter / fmaxf(uni, 1e-9f) >= 0.5f) sup = 1;
        }
        if (64 + lane < nsel) {
          float yy1 = fmaxf(sb1.x, by1), xx1 = fmaxf(sb1.y, bxx1);
          float yy2 = fminf(sb1.z, by2), xx2 = fminf(sb1.w, bxx2);
          float inter = fmaxf(yy2 - yy1, 0.f) * fmaxf(xx2 - xx1, 0.f);
          float uni = sa1 + areac - inter;
          if (inter / fmaxf(uni, 1e-9f) >= 0.5f) sup = 1;
        }
        if (!__any(sup)) {
          if (nsel == lane)      { sb0 = bx; sa0 = areac; }
          if (nsel == 64 + lane) { sb1 = bx; sa1 = areac; }
          if (lane == 0) { dsc[nsel] = v; dbx[nsel] = bx; }
          ++nsel;
        }
      }
    }

    if (nsel >= TT || lo <= 0.0f) {
      done = true;
    } else {
      cur_hi = lo;
      float nlo = lo - 0.03f;
      lo = (nlo <= 0.31f) ? 0.0f : nlo;
    }
  }
  // sentinel for empty slots
  for (int t = nsel + lane; t < TT; t += 64) dsc[t] = -INFINITY;
}

// ---------- K3: per-batch 80-way merge top-100 (lists are sorted desc, j=100c+t monotone in c) ----------
__global__ __launch_bounds__(64) void topk_merge(const float* __restrict__ det_score,
                                                 const float* __restrict__ det_box,
                                                 float* __restrict__ out) {
  __shared__ float ds[CC * TT];
  __shared__ int widx[TT];
  __shared__ float wval[TT];
  int b = blockIdx.x, lane = threadIdx.x;
  for (int i = lane; i < CC * TT; i += 64) ds[i] = det_score[(size_t)b * CC * TT + i];
  __builtin_amdgcn_wave_barrier();

  int h0 = 0, h1 = 0;
  int c1 = 64 + lane;
  bool has1 = lane < (CC - 64);
  float hv0 = ds[lane * TT];
  float hv1 = has1 ? ds[c1 * TT] : -INFINITY;

  for (int r = 0; r < TT; ++r) {
    float v = hv0; int cw = lane;
    if (has1 && hv1 > hv0) { v = hv1; cw = c1; }
    argmax_f_i(v, cw);                 // tie -> smaller class -> smaller global j
    if (cw == lane) {
      widx[r] = cw * TT + h0; wval[r] = v;
      ++h0; hv0 = (h0 < TT) ? ds[lane * TT + h0] : -INFINITY;
    } else if (has1 && cw == c1) {
      widx[r] = cw * TT + h1; wval[r] = v;
      ++h1; hv1 = (h1 < TT) ? ds[c1 * TT + h1] : -INFINITY;
    }
    __builtin_amdgcn_wave_barrier();
  }

  float* ob = out + (size_t)b * TT * 4;            // [0,3200)
  float* os = out + BB * TT * 4 + (size_t)b * TT;  // [3200,4000)
  float* ol = out + BB * TT * 5 + (size_t)b * TT;  // [4000,4800)
  int vc = 0;
  for (int t = lane; t < TT; t += 64) {
    float v = wval[t]; int wi = widx[t];
    bool valid = (v != -INFINITY);
    float4 bx = make_float4(0.f, 0.f, 0.f, 0.f);
    if (valid) bx = *(const float4*)(det_box + ((size_t)b * CC * TT + wi) * 4);
    ((float4*)ob)[t] = bx;
    os[t] = valid ? v : 0.0f;
    ol[t] = valid ? (float)(wi / TT) : 0.0f;
    vc += valid ? 1 : 0;
  }
#pragma unroll
  for (int d = 1; d < 64; d <<= 1) vc += __shfl_xor(vc, d);
  if (lane == 0) out[BB * TT * 5 + BB * TT + b] = (float)vc;
}

// ---------- launch ----------
extern "C" void kernel_launch(void* const* d_in, const int* in_sizes, int n_in,
                              void* d_out, int out_size, void* d_ws, size_t ws_size,
                              hipStream_t stream) {
  const float* boxes  = (const float*)d_in[0];   // (8,16384,4)
  const float* scores = (const float*)d_in[1];   // (8,16384,80)
  float* out = (float*)d_out;                    // 4808 floats

  const size_t TS_BYTES  = (size_t)BB * CC * NN * 4;   // 40 MiB
  const size_t DSC_BYTES = (size_t)BB * CC * TT * 4;
  const size_t DBX_BYTES = (size_t)BB * CC * TT * 16;
  int use_ts = (ws_size >= TS_BYTES + DSC_BYTES + DBX_BYTES) ? 1 : 0;

  char* ws = (char*)d_ws;
  float* ts        = use_ts ? (float*)ws : nullptr;
  float* det_score = (float*)(ws + (use_ts ? TS_BYTES : 0));
  float* det_box   = (float*)(ws + (use_ts ? TS_BYTES : 0) + DSC_BYTES);

  if (use_ts) {
    transpose_scores<<<BB * (NN / 64), 256, 0, stream>>>(scores, ts);
  }
  nms_kernel<<<BB * CC, 64, 0, stream>>>(boxes, scores, ts, use_ts, det_score, det_box);
  topk_merge<<<BB, 64, 0, stream>>>(det_score, det_box, out);
}